// Round 1
// baseline (21.171 us; speedup 1.0000x reference)
//
#include <hip/hip_runtime.h>

#define DD 128   // feature dim, fixed by the reference

// Per-element update: z = x*a + c; z2 = z*z; p *= (1 - z2)  [as fma(-z2,p,p)]; s += z2.
#define UPD4(P, S, XV)                                                        \
    {                                                                         \
        float z, z2;                                                          \
        z = fmaf((XV).x, av.x, cv.x); z2 = z * z; P = fmaf(-z2, P, P); S += z2; \
        z = fmaf((XV).y, av.y, cv.y); z2 = z * z; P = fmaf(-z2, P, P); S += z2; \
        z = fmaf((XV).z, av.z, cv.z); z2 = z * z; P = fmaf(-z2, P, P); S += z2; \
        z = fmaf((XV).w, av.w, cv.w); z2 = z * z; P = fmaf(-z2, P, P); S += z2; \
    }

__global__ __launch_bounds__(512, 4)
void wavelet_prod_kernel(const float* __restrict__ x,
                         const float* __restrict__ bias,
                         const float* __restrict__ scale,
                         float* __restrict__ out,
                         int B, int N)
{
    // a = 1/scale, c = -bias/scale for this block's 64 n-rows, full D=128.
    // Stored as float4 slots [64 rows][32 quads], quad index XOR-swizzled by (row&7)
    // so the compute-phase read (all lanes same quad, different rows) spreads
    // across all 32 LDS banks instead of a 32-way same-bank conflict.
    __shared__ float4 a_s[64 * 32];
    __shared__ float4 c_s[64 * 32];

    const int tid  = threadIdx.x;
    const int lane = tid & 63;
    const int wave = tid >> 6;

    const int n0 = blockIdx.x * 64;   // 64 n per block (one per lane)
    const int bb = blockIdx.y * 32;   // 32 b per block (4 per wave)

    // ---- one-time staging: 64x128 bias/scale tile -> a,c in LDS ----
    {
        const float4* b4 = (const float4*)(bias  + (size_t)n0 * DD);
        const float4* s4 = (const float4*)(scale + (size_t)n0 * DD);
        #pragma unroll
        for (int k = 0; k < 4; ++k) {
            int flat = tid + k * 512;          // 0..2047 float4 slots of the tile
            int r = flat >> 5;                 // row within tile (0..63)
            int q = flat & 31;                 // d-quad (0..31)
            float4 sv = s4[flat];
            float4 bv = b4[flat];
            float4 av, cv;
            av.x = 1.0f / sv.x; av.y = 1.0f / sv.y;
            av.z = 1.0f / sv.z; av.w = 1.0f / sv.w;
            cv.x = -bv.x * av.x; cv.y = -bv.y * av.y;
            cv.z = -bv.z * av.z; cv.w = -bv.w * av.w;
            int dst = r * 32 + (q ^ (r & 7));
            a_s[dst] = av;
            c_s[dst] = cv;
        }
    }
    __syncthreads();

    // Wave-uniform b-row base: encourage scalar (SMEM) loads for x.
    const int b0 = __builtin_amdgcn_readfirstlane(bb + wave * 4);
    const float4* xr = (const float4*)(x + (size_t)b0 * DD);  // rows stride 32 float4

    const float4* arow = a_s + lane * 32;
    const float4* crow = c_s + lane * 32;
    const int sw = lane & 7;

    float p0 = 1.f, p1 = 1.f, p2 = 1.f, p3 = 1.f;
    float s0 = 0.f, s1 = 0.f, s2 = 0.f, s3 = 0.f;

    const float kexp = -0.7213475204444817f;  // -0.5 * log2(e)

    #pragma unroll
    for (int f = 0; f < 8; ++f) {             // 8 folds of 16 d
        #pragma unroll
        for (int cc = 0; cc < 4; ++cc) {      // 4 quads of 4 d
            const int q    = f * 4 + cc;
            const int slot = q ^ sw;
            float4 av = arow[slot];
            float4 cv = crow[slot];
            float4 x0 = xr[q];
            float4 x1 = xr[32 + q];
            float4 x2 = xr[64 + q];
            float4 x3 = xr[96 + q];
            UPD4(p0, s0, x0);
            UPD4(p1, s1, x1);
            UPD4(p2, s2, x2);
            UPD4(p3, s3, x3);
        }
        // Fold the Gaussian factor every 16 d: keeps p from overflowing
        // (p tracks exp of the running log-product, which drifts downward).
        p0 *= exp2f(s0 * kexp); s0 = 0.f;
        p1 *= exp2f(s1 * kexp); s1 = 0.f;
        p2 *= exp2f(s2 * kexp); s2 = 0.f;
        p3 *= exp2f(s3 * kexp); s3 = 0.f;
    }

    float* o = out + (size_t)b0 * N + n0 + lane;
    o[0 * N] = p0;
    o[1 * N] = p1;
    o[2 * N] = p2;
    o[3 * N] = p3;
}

extern "C" void kernel_launch(void* const* d_in, const int* in_sizes, int n_in,
                              void* d_out, int out_size, void* d_ws, size_t ws_size,
                              hipStream_t stream)
{
    const float* x     = (const float*)d_in[0];
    const float* bias  = (const float*)d_in[1];
    const float* scale = (const float*)d_in[2];
    float* out = (float*)d_out;

    const int B = in_sizes[0] / DD;   // 2048
    const int N = in_sizes[1] / DD;   // 512

    dim3 grid(N / 64, B / 32);        // (8, 64) = 512 blocks
    wavelet_prod_kernel<<<grid, 512, 0, stream>>>(x, bias, scale, out, B, N);
}